// Round 3
// baseline (77.947 us; speedup 1.0000x reference)
//
#include <hip/hip_runtime.h>
#include <math.h>

#define N_WIRES 13
#define DIM 8192
#define N_LAYERS 3
#define N_OUT 10
#define BATCH 512
#define NTHREADS 512

// Gate on a register bit: pairs (k0, k0|MASK) within the 16 per-thread amps.
#define REG_GATE(MASK, W) do { \
    const float u0r=uu[l][W][0], u0i=uu[l][W][1], u1r=uu[l][W][2], u1i=uu[l][W][3]; \
    const float u2r=uu[l][W][4], u2i=uu[l][W][5], u3r=uu[l][W][6], u3i=uu[l][W][7]; \
    _Pragma("unroll") \
    for (int k0 = 0; k0 < 16; ++k0) { \
        if (k0 & (MASK)) continue; \
        const int k1 = k0 | (MASK); \
        const float a0r=ar[k0], a0i=ai[k0], a1r=ar[k1], a1i=ai[k1]; \
        ar[k0] = u0r*a0r - u0i*a0i + u1r*a1r - u1i*a1i; \
        ai[k0] = u0r*a0i + u0i*a0r + u1r*a1i + u1i*a1r; \
        ar[k1] = u2r*a0r - u2i*a0i + u3r*a1r - u3i*a1i; \
        ai[k1] = u2r*a0i + u2i*a0r + u3r*a1i + u3i*a1r; \
    } \
} while (0)

// Gate on a lane bit: partner amplitudes via shfl_xor; lane computes its own row.
#define SHFL_GATE(MASK, W, BITP) do { \
    const float v0r=uu[l][W][0], v0i=uu[l][W][1], v1r=uu[l][W][2], v1i=uu[l][W][3]; \
    const float v2r=uu[l][W][4], v2i=uu[l][W][5], v3r=uu[l][W][6], v3i=uu[l][W][7]; \
    const bool hb = (tid >> (BITP)) & 1; \
    const float uar = hb ? v3r : v0r, uai = hb ? v3i : v0i; \
    const float upr = hb ? v2r : v1r, upi = hb ? v2i : v1i; \
    _Pragma("unroll") \
    for (int k = 0; k < 16; ++k) { \
        const float prr = __shfl_xor(ar[k], (MASK)); \
        const float pii = __shfl_xor(ai[k], (MASK)); \
        const float nr = uar*ar[k] - uai*ai[k] + upr*prr - upi*pii; \
        const float ni = uar*ai[k] + uai*ar[k] + upr*pii + upi*prr; \
        ar[k] = nr; ai[k] = ni; \
    } \
} while (0)

__device__ __forceinline__ void cmul(float& cr, float& ci,
                                     float xr, float xi, float yr, float yi) {
    cr = xr*yr - xi*yi;
    ci = xr*yi + xi*yr;
}

__global__ __launch_bounds__(NTHREADS, 2) void vqc_kernel(
    const float* __restrict__ inputs,
    const float* __restrict__ weights,
    const float* __restrict__ embed,
    float* __restrict__ out)
{
    __shared__ float2 s2[DIM];
    __shared__ float uu[N_LAYERS][N_WIRES][8];
    __shared__ float co[N_LAYERS][N_WIRES];
    __shared__ float ga[N_LAYERS][N_WIRES];
    __shared__ float eB[N_LAYERS][16][2];
    __shared__ float G3t[N_LAYERS][2];
    __shared__ float G12t[N_LAYERS][2];
    __shared__ float red[NTHREADS / 64][N_OUT];

    const int b   = blockIdx.x;
    const int tid = threadIdx.x;

    // ---- setup stage 1: per-(layer,wire) params + U matrices ----
    if (tid < N_LAYERS * N_WIRES) {
        const int l = tid / N_WIRES;
        const int w = tid - l * N_WIRES;
        const int base = (l * N_WIRES + w) * 3;
        const float om = embed[base + 0];
        const float bi = embed[base + 1];
        const float gm = embed[base + 2];
        co[l][w] = inputs[b * N_WIRES + w] * om + bi;
        ga[l][w] = gm;

        const float phi = weights[base + 0];
        const float th  = weights[base + 1];
        const float omg = weights[base + 2];
        float c, s, ca, sa, cb, sb;
        __sincosf(0.5f * th, &s, &c);
        __sincosf(0.5f * (phi + omg), &sa, &ca);
        __sincosf(0.5f * (phi - omg), &sb, &cb);
        uu[l][w][0] =  ca * c;  uu[l][w][1] = -sa * c;   // U00
        uu[l][w][2] = -cb * s;  uu[l][w][3] = -sb * s;   // U01
        uu[l][w][4] =  cb * s;  uu[l][w][5] = -sb * s;   // U10
        uu[l][w][6] =  ca * c;  uu[l][w][7] =  sa * c;   // U11

        if (w == 3)  { float s2v, c2; __sincosf(2.f * gm, &s2v, &c2); G3t[l][0]  = c2; G3t[l][1]  = s2v; }
        if (w == 12) { float s2v, c2; __sincosf(2.f * gm, &s2v, &c2); G12t[l][0] = c2; G12t[l][1] = s2v; }
    }
    __syncthreads();

    // ---- setup stage 2: k-part phase table (bits 9..12 of x = k) ----
    if (tid < N_LAYERS * 16) {
        const int l = tid >> 4;
        const int k = tid & 15;
        float B = 0.f;
        if (k & 8) B -= 2.f * co[l][0];           // x12 -> wire 0
        if (k & 4) B -= 2.f * co[l][1];
        if (k & 2) B -= 2.f * co[l][2];
        if (k & 1) B -= 2.f * co[l][3];
        if (((k >> 3) ^ (k >> 2)) & 1) B -= 2.f * ga[l][0];   // e12
        if (((k >> 2) ^ (k >> 1)) & 1) B -= 2.f * ga[l][1];   // e11
        if (((k >> 1) ^  k      ) & 1) B -= 2.f * ga[l][2];   // e10
        float sB, cB; __sincosf(B, &sB, &cB);
        eB[l][k][0] = cB; eB[l][k][1] = -sB;      // exp(-iB)
    }
    __syncthreads();

    float ar[16], ai[16];

    #pragma unroll 1
    for (int l = 0; l < N_LAYERS; ++l) {
        // ===== Pass A: x = tid | (k<<9); phase + wires 0-3 (reg) + 8-12 (shfl) =====
        float S = 0.f;
        #pragma unroll
        for (int w = 0; w < N_WIRES; ++w) S += co[l][w] + ga[l][w];
        float A = S;
        #pragma unroll
        for (int w = 4; w <= 12; ++w)
            if ((tid >> (12 - w)) & 1) A -= 2.f * co[l][w];
        #pragma unroll
        for (int w = 4; w <= 11; ++w)
            if (((tid >> (12 - w)) ^ (tid >> (11 - w))) & 1) A -= 2.f * ga[l][w];

        float sA, cA; __sincosf(A, &sA, &cA);
        const float e0r = cA, e0i = -sA;          // exp(-iA)
        const float g3r = G3t[l][0],  g3i = G3t[l][1];    // exp(+2i*gamma3)
        const float gcr = G12t[l][0], gci = G12t[l][1];   // exp(+2i*gamma12)
        float e1r, e1i, e2r, e2i, e3r, e3i;
        cmul(e1r, e1i, e0r, e0i, g3r, g3i);
        cmul(e2r, e2i, e0r, e0i, gcr, gci);
        cmul(e3r, e3i, e1r, e1i, gcr, gci);
        const bool t8 = (tid >> 8) & 1;
        const bool t0 = (tid & 1) != 0;

        if (l == 0) {
            const float nrm = 0.011048543456039806f;   // 8192^-0.5
            #pragma unroll
            for (int k = 0; k < 16; ++k) {
                const bool c1 = ((k & 1) != 0) != t8;  // e9 = x9^x8
                const bool c2 = ((k & 8) != 0) != t0;  // e0 = x0^x12
                const float Er = c1 ? (c2 ? e3r : e1r) : (c2 ? e2r : e0r);
                const float Ei = c1 ? (c2 ? e3i : e1i) : (c2 ? e2i : e0i);
                float fr, fi;
                cmul(fr, fi, Er, Ei, eB[l][k][0], eB[l][k][1]);
                ar[k] = nrm * fr; ai[k] = nrm * fi;
            }
        } else {
            #pragma unroll
            for (int k = 0; k < 16; ++k) {
                const bool c1 = ((k & 1) != 0) != t8;
                const bool c2 = ((k & 8) != 0) != t0;
                const float Er = c1 ? (c2 ? e3r : e1r) : (c2 ? e2r : e0r);
                const float Ei = c1 ? (c2 ? e3i : e1i) : (c2 ? e2i : e0i);
                float fr, fi;
                cmul(fr, fi, Er, Ei, eB[l][k][0], eB[l][k][1]);
                const float2 v = s2[tid + (k << 9)];
                ar[k] = v.x * fr - v.y * fi;
                ai[k] = v.x * fi + v.y * fr;
            }
        }

        REG_GATE(8, 0);   // wire 0 <-> x bit 12 <-> k bit 3
        REG_GATE(4, 1);
        REG_GATE(2, 2);
        REG_GATE(1, 3);
        SHFL_GATE(16, 8, 4);   // wire 8 <-> x bit 4 (lane bit)
        SHFL_GATE(8,  9, 3);
        SHFL_GATE(4, 10, 2);
        SHFL_GATE(2, 11, 1);
        SHFL_GATE(1, 12, 0);

        #pragma unroll
        for (int k = 0; k < 16; ++k)
            s2[tid + (k << 9)] = make_float2(ar[k], ai[k]);
        __syncthreads();

        // ===== Pass B: x = (tid>>5)<<9 | k<<5 | (tid&31); wires 4-7 (reg) =====
        const int baseB = ((tid >> 5) << 9) | (tid & 31);
        #pragma unroll
        for (int k = 0; k < 16; ++k) {
            const float2 v = s2[baseB | (k << 5)];
            ar[k] = v.x; ai[k] = v.y;
        }
        REG_GATE(8, 4);   // wire 4 <-> x bit 8 <-> k bit 3
        REG_GATE(4, 5);
        REG_GATE(2, 6);
        REG_GATE(1, 7);   // wire 7 <-> x bit 5 <-> k bit 0

        if (l < N_LAYERS - 1) {
            // fused CNOT-ring permutation: scatter to y = sigma^{-1}(x)
            // y_j = XOR_{m>=j} x_m (j<=11); y_12 = (suffix parity at 0) ^ x_12
            #pragma unroll
            for (int k = 0; k < 16; ++k) {
                const int x = baseB | (k << 5);
                int t = x ^ (x >> 1); t ^= t >> 2; t ^= t >> 4; t ^= t >> 8;
                const int y = (t & 0x0FFF) | (((t ^ (x >> 12)) & 1) << 12);
                s2[y] = make_float2(ar[k], ai[k]);
            }
            __syncthreads();
        }
    }

    // ---- fused readout: signs from final (permuted) index y ----
    float acc[N_OUT];
    #pragma unroll
    for (int o = 0; o < N_OUT; ++o) acc[o] = 0.f;

    {
        const int baseB = ((tid >> 5) << 9) | (tid & 31);
        #pragma unroll
        for (int k = 0; k < 16; ++k) {
            const int x = baseB | (k << 5);
            int t = x ^ (x >> 1); t ^= t >> 2; t ^= t >> 4; t ^= t >> 8;
            const int y = (t & 0x0FFF) | (((t ^ (x >> 12)) & 1) << 12);
            const float p = ar[k] * ar[k] + ai[k] * ai[k];
            #pragma unroll
            for (int o = 0; o < N_OUT; ++o)
                acc[o] += ((y >> (12 - o)) & 1) ? -p : p;
        }
    }

    #pragma unroll
    for (int off = 32; off >= 1; off >>= 1) {
        #pragma unroll
        for (int o = 0; o < N_OUT; ++o) acc[o] += __shfl_down(acc[o], off);
    }
    const int wave = tid >> 6;
    const int lane = tid & 63;
    if (lane == 0) {
        #pragma unroll
        for (int o = 0; o < N_OUT; ++o) red[wave][o] = acc[o];
    }
    __syncthreads();
    if (tid < N_OUT) {
        float s = 0.f;
        #pragma unroll
        for (int w = 0; w < NTHREADS / 64; ++w) s += red[w][tid];
        out[b * N_OUT + tid] = s;
    }
}

extern "C" void kernel_launch(void* const* d_in, const int* in_sizes, int n_in,
                              void* d_out, int out_size, void* d_ws, size_t ws_size,
                              hipStream_t stream) {
    const float* inputs  = (const float*)d_in[0];
    const float* weights = (const float*)d_in[1];
    const float* embed   = (const float*)d_in[2];
    float* out = (float*)d_out;
    vqc_kernel<<<BATCH, NTHREADS, 0, stream>>>(inputs, weights, embed, out);
}

// Round 4
// 73.359 us; speedup vs baseline: 1.0625x; 1.0625x over previous
//
#include <hip/hip_runtime.h>
#include <math.h>

#define N_WIRES 13
#define DIM 8192
#define N_LAYERS 3
#define N_OUT 10
#define BATCH 512
#define NTHREADS 512

__device__ __forceinline__ void cmul(float& cr, float& ci,
                                     float xr, float xi, float yr, float yi) {
    cr = xr*yr - xi*yi;
    ci = xr*yi + xi*yr;
}

// Gate on a register bit: pairs (k0, k0|MASK) within the 16 per-thread amps.
// uA = (u00r,u00i,u01r,u01i), uB = (u10r,u10i,u11r,u11i) -> 2x ds_read_b128.
#define REG_GATE(MASK, W) do { \
    const float4 uA = uu4[l][W][0]; \
    const float4 uB = uu4[l][W][1]; \
    _Pragma("unroll") \
    for (int k0 = 0; k0 < 16; ++k0) { \
        if (k0 & (MASK)) continue; \
        const int k1 = k0 | (MASK); \
        const float a0r=ar[k0], a0i=ai[k0], a1r=ar[k1], a1i=ai[k1]; \
        ar[k0] = uA.x*a0r - uA.y*a0i + uA.z*a1r - uA.w*a1i; \
        ai[k0] = uA.x*a0i + uA.y*a0r + uA.z*a1i + uA.w*a1r; \
        ar[k1] = uB.x*a0r - uB.y*a0i + uB.z*a1r - uB.w*a1i; \
        ai[k1] = uB.x*a0i + uB.y*a0r + uB.z*a1i + uB.w*a1r; \
    } \
} while (0)

// Gate on lane bit 0 (x bit 0): partner via ds_swizzle xor-1 (0x041F).
#define SWZ1_GATE(W) do { \
    const float4 uA = uu4[l][W][0]; \
    const float4 uB = uu4[l][W][1]; \
    const bool hb = (tid & 1) != 0; \
    const float uar = hb ? uB.z : uA.x, uai = hb ? uB.w : uA.y; \
    const float upr = hb ? uB.x : uA.z, upi = hb ? uB.y : uA.w; \
    _Pragma("unroll") \
    for (int k = 0; k < 16; ++k) { \
        const float prr = __int_as_float(__builtin_amdgcn_ds_swizzle(__float_as_int(ar[k]), 0x041F)); \
        const float pii = __int_as_float(__builtin_amdgcn_ds_swizzle(__float_as_int(ai[k]), 0x041F)); \
        const float nr = uar*ar[k] - uai*ai[k] + upr*prr - upi*pii; \
        const float ni = uar*ai[k] + uai*ar[k] + upr*pii + upi*prr; \
        ar[k] = nr; ai[k] = ni; \
    } \
} while (0)

__global__ __launch_bounds__(NTHREADS, 2) void vqc_kernel(
    const float* __restrict__ inputs,
    const float* __restrict__ weights,
    const float* __restrict__ embed,
    float* __restrict__ out)
{
    __shared__ float2 s2[DIM];                       // state, XOR-swizzled addressing
    __shared__ float4 uu4[N_LAYERS][N_WIRES][2];     // Rot matrices
    __shared__ float  co[N_LAYERS][N_WIRES];
    __shared__ float  ga[N_LAYERS][N_WIRES];
    __shared__ float2 Ek[N_LAYERS][16];              // exp(-i(S - 2*C_k)), k = x bits 12..9
    __shared__ float2 Eh[N_LAYERS][8];               // exp(+2i*C_h),  h = x bits 8..6
    __shared__ float2 El[N_LAYERS][64];              // exp(+2i*C_lo), lo = x bits 5..0
    __shared__ float2 G3[N_LAYERS], G12[N_LAYERS], G6[N_LAYERS];  // exp(+2i*gamma)
    __shared__ float  red[NTHREADS / 64][N_OUT];

    const int b   = blockIdx.x;
    const int tid = threadIdx.x;

    // ---- setup stage 1: co/ga + U matrices + boundary gamma factors ----
    if (tid < N_LAYERS * N_WIRES) {
        const int l = tid / N_WIRES;
        const int w = tid - l * N_WIRES;
        const int base = (l * N_WIRES + w) * 3;
        const float om = embed[base + 0];
        const float bi = embed[base + 1];
        const float gm = embed[base + 2];
        co[l][w] = inputs[b * N_WIRES + w] * om + bi;
        ga[l][w] = gm;

        const float phi = weights[base + 0];
        const float th  = weights[base + 1];
        const float omg = weights[base + 2];
        float c, s, ca, sa, cb, sb;
        __sincosf(0.5f * th, &s, &c);
        __sincosf(0.5f * (phi + omg), &sa, &ca);
        __sincosf(0.5f * (phi - omg), &sb, &cb);
        uu4[l][w][0] = make_float4( ca * c, -sa * c, -cb * s, -sb * s);  // U00,U01
        uu4[l][w][1] = make_float4( cb * s, -sb * s,  ca * c,  sa * c);  // U10,U11

        if (w == 3 || w == 6 || w == 12) {
            float s2v, c2v; __sincosf(2.f * gm, &s2v, &c2v);
            if (w == 3)  G3[l]  = make_float2(c2v, s2v);
            if (w == 6)  G6[l]  = make_float2(c2v, s2v);
            if (w == 12) G12[l] = make_float2(c2v, s2v);
        }
    }
    __syncthreads();

    // ---- setup stage 2: phase tables ----
    if (tid < N_LAYERS * 16) {                      // Ek (folds S)
        const int l = tid >> 4, k = tid & 15;
        float S = 0.f;
        #pragma unroll
        for (int w = 0; w < N_WIRES; ++w) S += co[l][w] + ga[l][w];
        const int b3 = (k >> 3) & 1, b2 = (k >> 2) & 1, b1 = (k >> 1) & 1, b0 = k & 1;
        float v = S;
        if (b3) v -= 2.f * co[l][0];
        if (b2) v -= 2.f * co[l][1];
        if (b1) v -= 2.f * co[l][2];
        if (b0) v -= 2.f * co[l][3];
        if (b3 ^ b2) v -= 2.f * ga[l][0];
        if (b2 ^ b1) v -= 2.f * ga[l][1];
        if (b1 ^ b0) v -= 2.f * ga[l][2];
        float sv, cv; __sincosf(v, &sv, &cv);
        Ek[l][k] = make_float2(cv, -sv);
    }
    if (tid >= 64 && tid < 64 + N_LAYERS * 8) {     // Eh
        const int t = tid - 64, l = t >> 3, h = t & 7;
        const int b8 = (h >> 2) & 1, b7 = (h >> 1) & 1, b6 = h & 1;
        float T = 0.f;
        if (b8) T += co[l][4];
        if (b7) T += co[l][5];
        if (b6) T += co[l][6];
        if (b8 ^ b7) T += ga[l][4];
        if (b7 ^ b6) T += ga[l][5];
        float sv, cv; __sincosf(2.f * T, &sv, &cv);
        Eh[l][h] = make_float2(cv, sv);
    }
    if (tid >= 128 && tid < 128 + N_LAYERS * 64) {  // El
        const int t = tid - 128, l = t >> 6, m = t & 63;
        const int b5 = (m >> 5) & 1, b4 = (m >> 4) & 1, b3 = (m >> 3) & 1;
        const int b2 = (m >> 2) & 1, b1 = (m >> 1) & 1, b0 = m & 1;
        float T = 0.f;
        if (b5) T += co[l][7];
        if (b4) T += co[l][8];
        if (b3) T += co[l][9];
        if (b2) T += co[l][10];
        if (b1) T += co[l][11];
        if (b0) T += co[l][12];
        if (b5 ^ b4) T += ga[l][7];
        if (b4 ^ b3) T += ga[l][8];
        if (b3 ^ b2) T += ga[l][9];
        if (b2 ^ b1) T += ga[l][10];
        if (b1 ^ b0) T += ga[l][11];
        float sv, cv; __sincosf(2.f * T, &sv, &cv);
        El[l][m] = make_float2(cv, sv);
    }
    __syncthreads();

    // thread-constant addressing (state address = x ^ ((x>>5)&0xE), folded)
    const int tidA   = tid ^ ((tid >> 5) & 0xE);                       // pass A
    const int baseB  = ((tid >> 5) << 9) | (tid & 31);                 // pass B (^ k-const)
    const int xbaseC = ((tid >> 1) << 5) | (tid & 1);                  // pass C true x
    const int baseC  = xbaseC ^ ((tid >> 1) & 0xE);                    // pass C address
    const bool t8 = ((tid >> 8) & 1) != 0;
    const bool t0 = (tid & 1) != 0;
    const bool cG6 = (((tid >> 6) ^ (tid >> 5)) & 1) != 0;
    const int hidx = (tid >> 6) & 7;
    const int lidx = tid & 63;

    float ar[16], ai[16];

    #pragma unroll 1
    for (int l = 0; l < N_LAYERS; ++l) {
        // ===== Pass A: x = tid | (k<<9); phase + wires 0-3 =====
        float epr, epi;
        cmul(epr, epi, Eh[l][hidx].x, Eh[l][hidx].y, El[l][lidx].x, El[l][lidx].y);
        if (cG6) { float tr_, ti_; cmul(tr_, ti_, epr, epi, G6[l].x, G6[l].y); epr = tr_; epi = ti_; }
        float eg3r, eg3i; cmul(eg3r, eg3i, epr, epi, G3[l].x, G3[l].y);
        const float P0r = t8 ? eg3r : epr,  P0i = t8 ? eg3i : epi;   // k bit0 = 0
        const float P1r = t8 ? epr  : eg3r, P1i = t8 ? epi  : eg3i;  // k bit0 = 1
        const float g12r = G12[l].x, g12i = G12[l].y;
        const float Q0r = t0 ? g12r : 1.f, Q0i = t0 ? g12i : 0.f;    // k bit3 = 0
        const float Q1r = t0 ? 1.f : g12r, Q1i = t0 ? 0.f : g12i;    // k bit3 = 1
        float R00r, R00i, R01r, R01i, R10r, R10i, R11r, R11i;
        cmul(R00r, R00i, P0r, P0i, Q0r, Q0i);
        cmul(R01r, R01i, P0r, P0i, Q1r, Q1i);
        cmul(R10r, R10i, P1r, P1i, Q0r, Q0i);
        cmul(R11r, R11i, P1r, P1i, Q1r, Q1i);

        if (l == 0) {
            const float nrm = 0.011048543456039806f;   // 8192^-0.5
            #pragma unroll
            for (int k = 0; k < 16; ++k) {
                const float Rr = (k & 1) ? ((k & 8) ? R11r : R10r) : ((k & 8) ? R01r : R00r);
                const float Ri = (k & 1) ? ((k & 8) ? R11i : R10i) : ((k & 8) ? R01i : R00i);
                float fr, fi; cmul(fr, fi, Rr, Ri, Ek[l][k].x, Ek[l][k].y);
                ar[k] = nrm * fr; ai[k] = nrm * fi;
            }
        } else {
            #pragma unroll
            for (int k = 0; k < 16; ++k) {
                const float Rr = (k & 1) ? ((k & 8) ? R11r : R10r) : ((k & 8) ? R01r : R00r);
                const float Ri = (k & 1) ? ((k & 8) ? R11i : R10i) : ((k & 8) ? R01i : R00i);
                float fr, fi; cmul(fr, fi, Rr, Ri, Ek[l][k].x, Ek[l][k].y);
                const float2 v = s2[tidA | (k << 9)];
                ar[k] = v.x * fr - v.y * fi;
                ai[k] = v.x * fi + v.y * fr;
            }
        }

        REG_GATE(8, 0);   // wire 0 <-> x bit 12 (k bit 3)
        REG_GATE(4, 1);
        REG_GATE(2, 2);
        REG_GATE(1, 3);

        #pragma unroll
        for (int k = 0; k < 16; ++k)
            s2[tidA | (k << 9)] = make_float2(ar[k], ai[k]);
        __syncthreads();

        // ===== Pass B: x = (tid>>5)<<9 | k<<5 | (tid&31); wires 4-7 =====
        #pragma unroll
        for (int k = 0; k < 16; ++k) {
            const float2 v = s2[baseB ^ ((k << 5) | (k & 0xE))];
            ar[k] = v.x; ai[k] = v.y;
        }
        REG_GATE(8, 4);
        REG_GATE(4, 5);
        REG_GATE(2, 6);
        REG_GATE(1, 7);
        #pragma unroll
        for (int k = 0; k < 16; ++k)
            s2[baseB ^ ((k << 5) | (k & 0xE))] = make_float2(ar[k], ai[k]);
        __syncthreads();

        // ===== Pass C: x = (tid>>1)<<5 | k<<1 | (tid&1); wires 8-11 + 12 =====
        #pragma unroll
        for (int k = 0; k < 16; ++k) {
            const float2 v = s2[baseC ^ (k << 1)];
            ar[k] = v.x; ai[k] = v.y;
        }
        if (l < N_LAYERS - 1) __syncthreads();   // all loads done before scatter

        REG_GATE(8, 8);    // wire 8  <-> x bit 4 (k bit 3)
        REG_GATE(4, 9);
        REG_GATE(2, 10);
        REG_GATE(1, 11);
        SWZ1_GATE(12);     // wire 12 <-> x bit 0 (lane bit 0)

        if (l < N_LAYERS - 1) {
            // fused CNOT-ring permutation: scatter amp(x) to y = suffix-XOR(x)
            #pragma unroll
            for (int k = 0; k < 16; ++k) {
                const int x = xbaseC | (k << 1);
                int t = x ^ (x >> 1); t ^= t >> 2; t ^= t >> 4; t ^= t >> 8;
                const int y = (t & 0x0FFF) | (((t ^ (x >> 12)) & 1) << 12);
                s2[y ^ ((y >> 5) & 0xE)] = make_float2(ar[k], ai[k]);
            }
            __syncthreads();
        }
    }

    // ---- fused readout: signs from final (permuted) index y ----
    float acc[N_OUT];
    #pragma unroll
    for (int o = 0; o < N_OUT; ++o) acc[o] = 0.f;

    #pragma unroll
    for (int k = 0; k < 16; ++k) {
        const int x = xbaseC | (k << 1);
        int t = x ^ (x >> 1); t ^= t >> 2; t ^= t >> 4; t ^= t >> 8;
        const int y = (t & 0x0FFF) | (((t ^ (x >> 12)) & 1) << 12);
        const float p = ar[k] * ar[k] + ai[k] * ai[k];
        #pragma unroll
        for (int o = 0; o < N_OUT; ++o)
            acc[o] += ((y >> (12 - o)) & 1) ? -p : p;
    }

    #pragma unroll
    for (int off = 32; off >= 1; off >>= 1) {
        #pragma unroll
        for (int o = 0; o < N_OUT; ++o) acc[o] += __shfl_down(acc[o], off);
    }
    const int wave = tid >> 6;
    const int lane = tid & 63;
    if (lane == 0) {
        #pragma unroll
        for (int o = 0; o < N_OUT; ++o) red[wave][o] = acc[o];
    }
    __syncthreads();
    if (tid < N_OUT) {
        float s = 0.f;
        #pragma unroll
        for (int w = 0; w < NTHREADS / 64; ++w) s += red[w][tid];
        out[b * N_OUT + tid] = s;
    }
}

extern "C" void kernel_launch(void* const* d_in, const int* in_sizes, int n_in,
                              void* d_out, int out_size, void* d_ws, size_t ws_size,
                              hipStream_t stream) {
    const float* inputs  = (const float*)d_in[0];
    const float* weights = (const float*)d_in[1];
    const float* embed   = (const float*)d_in[2];
    float* out = (float*)d_out;
    vqc_kernel<<<BATCH, NTHREADS, 0, stream>>>(inputs, weights, embed, out);
}